// Round 1
// baseline (1158.179 us; speedup 1.0000x reference)
//
#include <hip/hip_runtime.h>

#define NN 4096
#define DIM 128

// One block per output row n. 256 threads.
// LDS: q[4][132] (padded: the four k-bases map to disjoint bank quads),
//      e_row[4096] score row, small reduction scratch.
__global__ __launch_bounds__(256) void gat_row_kernel(
    const float* __restrict__ hidden,   // [NN, DIM]
    const int*   __restrict__ adj,      // [NN, NN], values 0..4
    const float* __restrict__ W,        // [4, DIM]
    const float* __restrict__ bvec,     // [4]
    float*       __restrict__ out)      // [NN, DIM]
{
    __shared__ float q[4 * 132];
    __shared__ float e_row[NN];
    __shared__ float red[16];
    __shared__ float bias_s[4];

    const int n   = blockIdx.x;
    const int tid = threadIdx.x;
    const float NEG = -9.0e15f;

    // Stage q[k][d] = h[n][d] * W[k][d]
    for (int i = tid; i < 4 * DIM; i += 256) {
        int k = i >> 7, d = i & (DIM - 1);
        q[k * 132 + d] = hidden[(size_t)n * DIM + d] * W[k * DIM + d];
    }
    if (tid < 4) bias_s[tid] = bvec[tid];
    __syncthreads();

    // ---- Phase 1: scores e_row[m], track max ----
    float lmax = NEG;
    for (int m = tid; m < NN; m += 256) {
        int a = adj[(size_t)n * NN + m];
        float e = NEG;
        if (a != 0) {
            const float4* hm = (const float4*)(hidden + (size_t)m * DIM);
            const float4* qk = (const float4*)(q + (a - 1) * 132);  // 132*4B = 33*16B, aligned
            float acc0 = 0.f, acc1 = 0.f, acc2 = 0.f, acc3 = 0.f;
            for (int t = 0; t < DIM / 16; ++t) {
                float4 h0 = hm[4 * t + 0], h1 = hm[4 * t + 1];
                float4 h2 = hm[4 * t + 2], h3 = hm[4 * t + 3];
                float4 q0 = qk[4 * t + 0], q1 = qk[4 * t + 1];
                float4 q2 = qk[4 * t + 2], q3 = qk[4 * t + 3];
                acc0 += h0.x * q0.x + h0.y * q0.y + h0.z * q0.z + h0.w * q0.w;
                acc1 += h1.x * q1.x + h1.y * q1.y + h1.z * q1.z + h1.w * q1.w;
                acc2 += h2.x * q2.x + h2.y * q2.y + h2.z * q2.z + h2.w * q2.w;
                acc3 += h3.x * q3.x + h3.y * q3.y + h3.z * q3.z + h3.w * q3.w;
            }
            float s = (acc0 + acc1) + (acc2 + acc3) + bias_s[a - 1];
            e = (s >= 0.f) ? s : 0.2f * s;   // leaky_relu slope 0.2
        }
        e_row[m] = e;
        lmax = fmaxf(lmax, e);
    }
    // block max-reduce
    for (int off = 32; off >= 1; off >>= 1)
        lmax = fmaxf(lmax, __shfl_down(lmax, off, 64));
    if ((tid & 63) == 0) red[tid >> 6] = lmax;
    __syncthreads();
    if (tid == 0)
        red[8] = fmaxf(fmaxf(red[0], red[1]), fmaxf(red[2], red[3]));
    __syncthreads();
    const float rmax = red[8];

    // ---- Phase 2: exp + sum ----
    float lsum = 0.f;
    for (int m = tid; m < NN; m += 256) {
        float w = __expf(e_row[m] - rmax);   // masked: exp(-9e15 - rmax) -> 0
        e_row[m] = w;
        lsum += w;
    }
    for (int off = 32; off >= 1; off >>= 1)
        lsum += __shfl_down(lsum, off, 64);
    if ((tid & 63) == 0) red[tid >> 6] = lsum;
    __syncthreads();
    if (tid == 0)
        red[9] = (red[0] + red[1]) + (red[2] + red[3]);
    __syncthreads();
    const float inv = 1.0f / red[9];

    // ---- Phase 3: out[n,d] = sum_m w[m] * h[m,d] * inv ----
    const int d    = tid & (DIM - 1);   // 0..127 -> coalesced hidden reads
    const int half = tid >> 7;          // 0 or 1, splits the m range
    const float* hcol = hidden + d;
    float acc = 0.f;
    const int m0 = half * (NN / 2);
    for (int m = m0; m < m0 + NN / 2; m += 4) {
        float w0 = e_row[m + 0], w1 = e_row[m + 1];
        float w2 = e_row[m + 2], w3 = e_row[m + 3];
        acc += w0 * hcol[(size_t)(m + 0) * DIM];
        acc += w1 * hcol[(size_t)(m + 1) * DIM];
        acc += w2 * hcol[(size_t)(m + 2) * DIM];
        acc += w3 * hcol[(size_t)(m + 3) * DIM];
    }
    // combine the two halves via LDS (q is dead now; reuse as scratch)
    if (half == 1) q[d] = acc;
    __syncthreads();
    if (half == 0) out[(size_t)n * DIM + d] = (acc + q[d]) * inv;
}

extern "C" void kernel_launch(void* const* d_in, const int* in_sizes, int n_in,
                              void* d_out, int out_size, void* d_ws, size_t ws_size,
                              hipStream_t stream) {
    const float* hidden = (const float*)d_in[0];
    const int*   adj    = (const int*)d_in[1];
    const float* W      = (const float*)d_in[2];
    const float* b      = (const float*)d_in[3];
    float* out = (float*)d_out;

    gat_row_kernel<<<NN, 256, 0, stream>>>(hidden, adj, W, b, out);
}

// Round 2
// 187.330 us; speedup vs baseline: 6.1825x; 6.1825x over previous
//
#include <hip/hip_runtime.h>

#define NN 4096
#define DIM 128
#define TN 16            // rows per block
#define TM 128           // m-tile size
#define NTILES (NN / TM) // 32

typedef __attribute__((ext_vector_type(8))) short bf16x8;
typedef __attribute__((ext_vector_type(4))) float f32x4;

#define HR_STRIDE 136    // bf16 elems per Hrow row (pad 8 -> 272B, 16B aligned, stride%32dw==4)
#define HC_STRIDE 140    // bf16 elems per Hcol row (280B, 8B aligned)
#define P_STRIDE  136

__device__ inline unsigned short f2bf(float x) {
    union { float f; unsigned u; } v; v.f = x;
    unsigned r = v.u + 0x7FFFu + ((v.u >> 16) & 1u);
    return (unsigned short)(r >> 16);
}

__global__ __launch_bounds__(256, 2) void gat_flash_kernel(
    const float* __restrict__ hidden,   // [NN, DIM] fp32
    const int*   __restrict__ adj,      // [NN, NN] 0..4
    const float* __restrict__ W,        // [4, DIM]
    const float* __restrict__ bvec,     // [4]
    float*       __restrict__ out)      // [NN, DIM]
{
    __shared__ __align__(16) unsigned short Hrow[TM * HR_STRIDE];   // 34816 B
    __shared__ __align__(16) unsigned short Hcol[DIM * HC_STRIDE];  // 35840 B
    __shared__ __align__(16) unsigned short Pl[TN * P_STRIDE];      // 4352 B
    __shared__ float redmax[4][16];
    __shared__ float redsum[4][16];

    const int tid  = threadIdx.x;
    const int w    = tid >> 6;      // wave 0..3
    const int lane = tid & 63;
    const int g    = lane >> 4;     // quad group 0..3
    const int l15  = lane & 15;
    const int n0   = blockIdx.x * TN;
    const int msub = 32 * w;        // this wave's m-slice (scores) / d-slice (PV)
    const float NEG = -9.0e15f;

    const float b0 = bvec[0], b1 = bvec[1], b2 = bvec[2], b3 = bvec[3];

    // ---- Q staging: q[k][r][d] = h[n0+r][d] * W[k][d], bf16, aliased into Hrow ----
    {
        unsigned short* Q = Hrow;              // [64 rows][HR_STRIDE]
        int pair = tid >> 2;                   // 0..63 = k*16 + r
        int k = pair >> 4, r = pair & 15;
        int d0 = (tid & 3) * 32;
        const float* hrow = hidden + (size_t)(n0 + r) * DIM + d0;
        const float* wrow = W + k * DIM + d0;
        #pragma unroll
        for (int c = 0; c < 8; ++c) {
            float4 hv = *(const float4*)(hrow + 4 * c);
            float4 wv = *(const float4*)(wrow + 4 * c);
            ushort4 o;
            o.x = f2bf(hv.x * wv.x); o.y = f2bf(hv.y * wv.y);
            o.z = f2bf(hv.z * wv.z); o.w = f2bf(hv.w * wv.w);
            *(ushort4*)&Q[pair * HR_STRIDE + d0 + 4 * c] = o;
        }
    }
    __syncthreads();

    // Preload A-fragments: Af[k][ks] = Q[k][r=l15][d = ks*32 + 8g + 0..7]
    bf16x8 Af[4][4];
    #pragma unroll
    for (int k = 0; k < 4; ++k)
        #pragma unroll
        for (int ks = 0; ks < 4; ++ks)
            Af[k][ks] = *(const bf16x8*)&Hrow[(k * 16 + l15) * HR_STRIDE + ks * 32 + 8 * g];
    __syncthreads();   // before tile 0 overwrites Q region

    float mrow[4], lrow[4];
    f32x4 Oacc[2];
    #pragma unroll
    for (int t = 0; t < 4; ++t) { mrow[t] = -INFINITY; lrow[t] = 0.f; }
    Oacc[0] = (f32x4){0.f, 0.f, 0.f, 0.f};
    Oacc[1] = (f32x4){0.f, 0.f, 0.f, 0.f};

    for (int tile = 0; tile < NTILES; ++tile) {
        const int mt0 = tile * TM;

        // adj prefetch for this wave's score slice (issue early, used after mfma)
        int av[2][4];
        #pragma unroll
        for (int ct = 0; ct < 2; ++ct)
            #pragma unroll
            for (int t = 0; t < 4; ++t)
                av[ct][t] = adj[(size_t)(n0 + 4 * g + t) * NN + mt0 + msub + ct * 16 + l15];

        __syncthreads();   // A: previous tile's PV finished reading Hrow/Hcol/Pl

        // ---- stage H tile: bf16, both row-major and m-major layouts ----
        #pragma unroll
        for (int p = 0; p < 2; ++p) {
            int pi = tid + 256 * p;
            int mg = pi >> 5, dg = pi & 31;
            int m0 = mg * 8, d0 = dg * 4;
            float4 rows[8];
            #pragma unroll
            for (int i = 0; i < 8; ++i)
                rows[i] = *(const float4*)(hidden + (size_t)(mt0 + m0 + i) * DIM + d0);
            #pragma unroll
            for (int i = 0; i < 8; ++i) {
                ushort4 o;
                o.x = f2bf(rows[i].x); o.y = f2bf(rows[i].y);
                o.z = f2bf(rows[i].z); o.w = f2bf(rows[i].w);
                *(ushort4*)&Hrow[(m0 + i) * HR_STRIDE + d0] = o;
            }
            const float* rf = (const float*)rows;
            #pragma unroll
            for (int jj = 0; jj < 4; ++jj) {
                ushort4 a, b;
                a.x = f2bf(rf[0 * 4 + jj]); a.y = f2bf(rf[1 * 4 + jj]);
                a.z = f2bf(rf[2 * 4 + jj]); a.w = f2bf(rf[3 * 4 + jj]);
                b.x = f2bf(rf[4 * 4 + jj]); b.y = f2bf(rf[5 * 4 + jj]);
                b.z = f2bf(rf[6 * 4 + jj]); b.w = f2bf(rf[7 * 4 + jj]);
                *(ushort4*)&Hcol[(d0 + jj) * HC_STRIDE + m0]     = a;
                *(ushort4*)&Hcol[(d0 + jj) * HC_STRIDE + m0 + 4] = b;
            }
        }
        __syncthreads();   // staged

        // ---- scores: S[k] = Q_k @ H^T for m-slice [mt0+msub, +32) ----
        f32x4 S[4][2];
        #pragma unroll
        for (int k = 0; k < 4; ++k) {
            S[k][0] = (f32x4){0.f, 0.f, 0.f, 0.f};
            S[k][1] = (f32x4){0.f, 0.f, 0.f, 0.f};
        }
        #pragma unroll
        for (int ks = 0; ks < 4; ++ks) {
            #pragma unroll
            for (int ct = 0; ct < 2; ++ct) {
                bf16x8 B = *(const bf16x8*)&Hrow[(msub + ct * 16 + l15) * HR_STRIDE + ks * 32 + 8 * g];
                #pragma unroll
                for (int k = 0; k < 4; ++k)
                    S[k][ct] = __builtin_amdgcn_mfma_f32_16x16x32_bf16(Af[k][ks], B, S[k][ct], 0, 0, 0);
            }
        }

        // ---- selection + leaky-relu; C-layout: row = 4g+t, col = l15 ----
        float ev[2][4];
        float rmax[4] = {NEG, NEG, NEG, NEG};
        #pragma unroll
        for (int ct = 0; ct < 2; ++ct) {
            #pragma unroll
            for (int t = 0; t < 4; ++t) {
                int a = av[ct][t];
                float s = S[0][ct][t] + b0;
                s = (a == 2) ? S[1][ct][t] + b1 : s;
                s = (a == 3) ? S[2][ct][t] + b2 : s;
                s = (a == 4) ? S[3][ct][t] + b3 : s;
                float e = fmaxf(s, 0.2f * s);       // leaky_relu, slope 0.2
                e = (a == 0) ? NEG : e;
                ev[ct][t] = e;
                rmax[t] = fmaxf(rmax[t], e);
            }
        }
        // row max across the 16 cols held by the 16-lane group
        #pragma unroll
        for (int t = 0; t < 4; ++t) {
            float v = rmax[t];
            v = fmaxf(v, __shfl_xor(v, 1));
            v = fmaxf(v, __shfl_xor(v, 2));
            v = fmaxf(v, __shfl_xor(v, 4));
            v = fmaxf(v, __shfl_xor(v, 8));
            rmax[t] = v;
        }
        if (l15 == 0) {
            #pragma unroll
            for (int t = 0; t < 4; ++t) redmax[w][4 * g + t] = rmax[t];
        }
        __syncthreads();   // B: per-wave tile maxima visible

        float alpha[4], mnew[4];
        #pragma unroll
        for (int t = 0; t < 4; ++t) {
            int r = 4 * g + t;
            float tm = fmaxf(fmaxf(redmax[0][r], redmax[1][r]),
                             fmaxf(redmax[2][r], redmax[3][r]));
            float mn = fmaxf(mrow[t], tm);
            alpha[t] = __expf(mrow[t] - mn);   // exp(-inf)=0 on first tile
            mnew[t] = mn; mrow[t] = mn;
            lrow[t] *= alpha[t];
        }
        // P = exp(e - mnew), write bf16 to LDS, accumulate row sums
        float rs[4] = {0.f, 0.f, 0.f, 0.f};
        #pragma unroll
        for (int ct = 0; ct < 2; ++ct) {
            #pragma unroll
            for (int t = 0; t < 4; ++t) {
                float p = __expf(ev[ct][t] - mnew[t]);
                rs[t] += p;
                Pl[(4 * g + t) * P_STRIDE + msub + ct * 16 + l15] = f2bf(p);
            }
        }
        #pragma unroll
        for (int t = 0; t < 4; ++t) {
            float v = rs[t];
            v += __shfl_xor(v, 1); v += __shfl_xor(v, 2);
            v += __shfl_xor(v, 4); v += __shfl_xor(v, 8);
            rs[t] = v;
        }
        if (l15 == 0) {
            #pragma unroll
            for (int t = 0; t < 4; ++t) redsum[w][4 * g + t] = rs[t];
        }
        // rescale O accumulator (rows match C layout: row = 4g+t)
        #pragma unroll
        for (int t = 0; t < 4; ++t) { Oacc[0][t] *= alpha[t]; Oacc[1][t] *= alpha[t]; }
        __syncthreads();   // C: P + row sums visible

        #pragma unroll
        for (int t = 0; t < 4; ++t) {
            int r = 4 * g + t;
            lrow[t] += redsum[0][r] + redsum[1][r] + redsum[2][r] + redsum[3][r];
        }

        // ---- PV: O[16r][32d-slice] += P[16][128] @ H[128][d] ----
        #pragma unroll
        for (int ks = 0; ks < 4; ++ks) {
            bf16x8 Pa = *(const bf16x8*)&Pl[l15 * P_STRIDE + ks * 32 + 8 * g];
            #pragma unroll
            for (int dct = 0; dct < 2; ++dct) {
                int drow = msub + dct * 16 + l15;
                const unsigned short* hp = &Hcol[drow * HC_STRIDE + ks * 32 + 8 * g];
                ushort4 u0 = *(const ushort4*)hp;
                ushort4 u1 = *(const ushort4*)(hp + 4);
                bf16x8 Bv;
                Bv[0] = (short)u0.x; Bv[1] = (short)u0.y; Bv[2] = (short)u0.z; Bv[3] = (short)u0.w;
                Bv[4] = (short)u1.x; Bv[5] = (short)u1.y; Bv[6] = (short)u1.z; Bv[7] = (short)u1.w;
                Oacc[dct] = __builtin_amdgcn_mfma_f32_16x16x32_bf16(Pa, Bv, Oacc[dct], 0, 0, 0);
            }
        }
    }

    // ---- epilogue: normalize and store ----
    #pragma unroll
    for (int t = 0; t < 4; ++t) {
        float inv = 1.0f / lrow[t];
        size_t rowoff = (size_t)(n0 + 4 * g + t) * DIM + msub + l15;
        out[rowoff]      = Oacc[0][t] * inv;
        out[rowoff + 16] = Oacc[1][t] * inv;
    }
}

extern "C" void kernel_launch(void* const* d_in, const int* in_sizes, int n_in,
                              void* d_out, int out_size, void* d_ws, size_t ws_size,
                              hipStream_t stream) {
    const float* hidden = (const float*)d_in[0];
    const int*   adj    = (const int*)d_in[1];
    const float* W      = (const float*)d_in[2];
    const float* b      = (const float*)d_in[3];
    float* out = (float*)d_out;

    gat_flash_kernel<<<NN / TN, 256, 0, stream>>>(hidden, adj, W, b, out);
}